// Round 1
// baseline (450.644 us; speedup 1.0000x reference)
//
#include <hip/hip_runtime.h>
#include <cstdint>
#include <cstddef>

#define N_NODES 8192
#define INF 512
#define OUTF 256

typedef _Float16 f16;
typedef _Float16 f16x8 __attribute__((ext_vector_type(8)));
typedef float f32x4 __attribute__((ext_vector_type(4)));

__device__ __forceinline__ void async_copy16(void* lds_dst, const void* g_src) {
  __builtin_amdgcn_global_load_lds(
      (const __attribute__((address_space(1))) void*)g_src,
      (__attribute__((address_space(3))) void*)lds_dst,
      16, 0, 0);
}

// -------- Kernel 1: support_T[o][m] = (f16) sum_i W[i][o] * X[m][i] --------
// Computed as W^T (A-operand, transposed in LDS) times X (B-operand,
// k-contiguous already). Output writes are m-contiguous (coalesced).
__global__ __launch_bounds__(256) void gemm1_xw(
    const float* __restrict__ X, const float* __restrict__ W,
    f16* __restrict__ supT) {
  __shared__ __align__(16) f16 Asm[64][72];   // [o'][i']  W^T tile (pad 72)
  __shared__ __align__(16) f16 Bsm[128][72];  // [m'][i']  X tile   (pad 72)
  const int t = threadIdx.x;
  const int wave = t >> 6;
  const int lane = t & 63;
  const int q = lane >> 4;
  const int r = lane & 15;
  const int o0 = blockIdx.x * 64;   // 4 blocks
  const int m0 = blockIdx.y * 128;  // 64 blocks

  f32x4 acc[4][2];
#pragma unroll
  for (int i = 0; i < 4; ++i)
#pragma unroll
    for (int j = 0; j < 2; ++j)
      acc[i][j] = (f32x4){0.f, 0.f, 0.f, 0.f};

  const int a_o = t & 63;            // o within tile
  const int a_i = (t >> 6) * 16;     // i chunk
  const int b_m = t >> 1;            // m within tile
  const int b_i = (t & 1) * 32;      // i chunk
  const float* xrow = X + (size_t)(m0 + b_m) * INF + b_i;

  for (int kt = 0; kt < 8; ++kt) {
    const int k0 = kt * 64;
    // W^T tile: strided (transposing) reads, coalesced across lanes (o fast)
    {
      f16x8 h0, h1;
#pragma unroll
      for (int u = 0; u < 8; ++u)
        h0[u] = (f16)W[(size_t)(k0 + a_i + u) * OUTF + o0 + a_o];
#pragma unroll
      for (int u = 0; u < 8; ++u)
        h1[u] = (f16)W[(size_t)(k0 + a_i + 8 + u) * OUTF + o0 + a_o];
      *(f16x8*)&Asm[a_o][a_i] = h0;
      *(f16x8*)&Asm[a_o][a_i + 8] = h1;
    }
    // X tile: 32 contiguous fp32 per thread, cvt to f16
    {
      const float* xp = xrow + k0;
#pragma unroll
      for (int c = 0; c < 4; ++c) {
        f32x4 v0 = *(const f32x4*)(xp + c * 8);
        f32x4 v1 = *(const f32x4*)(xp + c * 8 + 4);
        f16x8 h;
#pragma unroll
        for (int u = 0; u < 4; ++u) {
          h[u] = (f16)v0[u];
          h[4 + u] = (f16)v1[u];
        }
        *(f16x8*)&Bsm[b_m][b_i + c * 8] = h;
      }
    }
    __syncthreads();
#pragma unroll
    for (int s = 0; s < 2; ++s) {
      f16x8 af[4], bf[2];
#pragma unroll
      for (int i = 0; i < 4; ++i)
        af[i] = *(const f16x8*)&Asm[i * 16 + r][s * 32 + q * 8];
#pragma unroll
      for (int j = 0; j < 2; ++j)
        bf[j] = *(const f16x8*)&Bsm[wave * 32 + j * 16 + r][s * 32 + q * 8];
#pragma unroll
      for (int i = 0; i < 4; ++i)
#pragma unroll
        for (int j = 0; j < 2; ++j)
          acc[i][j] = __builtin_amdgcn_mfma_f32_16x16x32_f16(af[i], bf[j],
                                                             acc[i][j], 0, 0, 0);
    }
    __syncthreads();
  }
  // C/D layout: row(o) = q*4+g, col(m) = r
#pragma unroll
  for (int i = 0; i < 4; ++i) {
#pragma unroll
    for (int j = 0; j < 2; ++j) {
      const int m = m0 + wave * 32 + j * 16 + r;
#pragma unroll
      for (int g = 0; g < 4; ++g) {
        const int o = o0 + i * 16 + q * 4 + g;
        supT[(size_t)o * N_NODES + m] = (f16)acc[i][j][g];
      }
    }
  }
}

// -------- Kernel 2: out[n][o] += sum_m adj[n][m]^2 * support_T[o][m] --------
// Block tile 64 (n) x 256 (o), BK=64 over m, split-K=2 via atomicAdd.
// 4 waves, each 64x64 => 4x4 tiles of 16x16x32 f16 MFMA, 64 acc VGPRs.
__global__ __launch_bounds__(256) void gemm2_adj(
    const float* __restrict__ adj, const f16* __restrict__ supT,
    float* __restrict__ out) {
  __shared__ __align__(16) f16 Asm[64][72];    // [n'][k'] adj^2 tile (pad 72)
  __shared__ __align__(16) f16 Bsm[256 * 64];  // [o][k'] support, XOR-swizzled chunks
  const int t = threadIdx.x;
  const int wave = t >> 6;
  const int lane = t & 63;
  const int q = lane >> 4;
  const int r = lane & 15;
  const int n0 = blockIdx.x * 64;
  const size_t m_base = (size_t)blockIdx.y * 4096;

  f32x4 acc[4][4];
#pragma unroll
  for (int i = 0; i < 4; ++i)
#pragma unroll
    for (int j = 0; j < 4; ++j)
      acc[i][j] = (f32x4){0.f, 0.f, 0.f, 0.f};

  const int a_row = t >> 2;        // n' 0..63
  const int a_col = (t & 3) * 16;  // k chunk
  const float* aptr = adj + (size_t)(n0 + a_row) * N_NODES + m_base + a_col;

  const int b_o = wave * 64 + (lane >> 3);  // + j*8 in loop
  const int b_kb = lane & 7;                // physical 16B chunk within row

  for (int kt = 0; kt < 64; ++kt) {
    // B: async global->LDS. LDS dest must be base + lane*16 (contiguous), so
    // the bank-conflict swizzle is applied to the SOURCE address:
    // physical[o][kb'] = logical[o][kb' ^ (o&7)]
#pragma unroll
    for (int j = 0; j < 8; ++j) {
      const int o = b_o + j * 8;
      const int kb = b_kb ^ (o & 7);
      const f16* src = supT + (size_t)o * N_NODES + m_base + kt * 64 + kb * 8;
      f16* dst = Bsm + (wave * 64 + j * 8) * 64;  // wave-uniform
      async_copy16(dst, src);
    }
    // A: 16 fp32 per thread, square, cvt f16, 2x ds_write_b128
    {
      const float* ap = aptr + kt * 64;
      f32x4 v0 = *(const f32x4*)(ap + 0);
      f32x4 v1 = *(const f32x4*)(ap + 4);
      f32x4 v2 = *(const f32x4*)(ap + 8);
      f32x4 v3 = *(const f32x4*)(ap + 12);
      f16x8 h0, h1;
#pragma unroll
      for (int u = 0; u < 4; ++u) {
        h0[u] = (f16)(v0[u] * v0[u]);
        h0[4 + u] = (f16)(v1[u] * v1[u]);
        h1[u] = (f16)(v2[u] * v2[u]);
        h1[4 + u] = (f16)(v3[u] * v3[u]);
      }
      *(f16x8*)&Asm[a_row][a_col] = h0;
      *(f16x8*)&Asm[a_row][a_col + 8] = h1;
    }
    __syncthreads();  // drains vmcnt (async loads) + lgkm before compute
#pragma unroll
    for (int s = 0; s < 2; ++s) {
      f16x8 af[4], bf[4];
#pragma unroll
      for (int i = 0; i < 4; ++i)
        af[i] = *(const f16x8*)&Asm[i * 16 + r][s * 32 + q * 8];
#pragma unroll
      for (int j = 0; j < 4; ++j) {
        const int o = wave * 64 + j * 16 + r;        // o&7 == r&7
        const int cc = (s * 4 + q) ^ (r & 7);        // un-swizzle
        bf[j] = *(const f16x8*)&Bsm[o * 64 + cc * 8];
      }
#pragma unroll
      for (int i = 0; i < 4; ++i)
#pragma unroll
        for (int j = 0; j < 4; ++j)
          acc[i][j] = __builtin_amdgcn_mfma_f32_16x16x32_f16(af[i], bf[j],
                                                             acc[i][j], 0, 0, 0);
    }
    __syncthreads();  // protect LDS before next stage
  }
  // split-K combine: device-scope fp32 atomics into zeroed out
#pragma unroll
  for (int i = 0; i < 4; ++i) {
#pragma unroll
    for (int g = 0; g < 4; ++g) {
      const int n = n0 + i * 16 + q * 4 + g;
      float* orow = out + (size_t)n * OUTF + wave * 64 + r;
#pragma unroll
      for (int j = 0; j < 4; ++j)
        atomicAdd(orow + j * 16, acc[i][j][g]);
    }
  }
}

// -------- Kernel 3: out = ELU(out + bias), in place, float4 --------
__global__ __launch_bounds__(256) void bias_elu(float* __restrict__ out,
                                                const float* __restrict__ bias) {
  const int idx = blockIdx.x * 256 + threadIdx.x;  // float4 index
  f32x4 v = ((const f32x4*)out)[idx];
  const f32x4 b = ((const f32x4*)bias)[idx & 63];  // OUTF/4 = 64
#pragma unroll
  for (int u = 0; u < 4; ++u) {
    const float x = v[u] + b[u];
    v[u] = x > 0.f ? x : expm1f(x);
  }
  ((f32x4*)out)[idx] = v;
}

extern "C" void kernel_launch(void* const* d_in, const int* in_sizes, int n_in,
                              void* d_out, int out_size, void* d_ws, size_t ws_size,
                              hipStream_t stream) {
  const float* X = (const float*)d_in[0];     // [8192, 512]
  const float* adj = (const float*)d_in[1];   // [8192, 8192]
  const float* W = (const float*)d_in[2];     // [512, 256]
  const float* bias = (const float*)d_in[3];  // [256]
  float* out = (float*)d_out;                 // [8192, 256] fp32
  f16* supT = (f16*)d_ws;                     // [256][8192] f16 = 4 MB

  hipMemsetAsync(d_out, 0, (size_t)out_size * sizeof(float), stream);
  gemm1_xw<<<dim3(4, 64), 256, 0, stream>>>(X, W, supT);
  gemm2_adj<<<dim3(128, 2), 256, 0, stream>>>(adj, supT, out);
  bias_elu<<<out_size / 1024, 256, 0, stream>>>(out, bias);
}

// Round 2
// 443.440 us; speedup vs baseline: 1.0162x; 1.0162x over previous
//
#include <hip/hip_runtime.h>
#include <cstdint>
#include <cstddef>

#define N_NODES 8192
#define INF 512
#define OUTF 256
#define SPLITK 8
#define MSLICE (N_NODES / SPLITK)  // 1024

typedef _Float16 f16;
typedef _Float16 f16x8 __attribute__((ext_vector_type(8)));
typedef float f32x4 __attribute__((ext_vector_type(4)));

__device__ __forceinline__ void async_copy16(void* lds_dst, const void* g_src) {
  __builtin_amdgcn_global_load_lds(
      (const __attribute__((address_space(1))) void*)g_src,
      (__attribute__((address_space(3))) void*)lds_dst,
      16, 0, 0);
}

__device__ __forceinline__ float elu(float x) { return x > 0.f ? x : expm1f(x); }

// -------- prep: X (fp32) -> Xh (f16), 8 elems/thread --------
__global__ __launch_bounds__(256) void cast_x(const float* __restrict__ X,
                                              f16* __restrict__ Xh) {
  const int idx = blockIdx.x * 256 + threadIdx.x;  // f16x8 index
  f32x4 v0 = ((const f32x4*)X)[idx * 2];
  f32x4 v1 = ((const f32x4*)X)[idx * 2 + 1];
  f16x8 h;
#pragma unroll
  for (int u = 0; u < 4; ++u) {
    h[u] = (f16)v0[u];
    h[4 + u] = (f16)v1[u];
  }
  ((f16x8*)Xh)[idx] = h;
}

// -------- prep: W [512][256] fp32 -> WhT [256][512] f16 --------
__global__ __launch_bounds__(256) void transpose_w(const float* __restrict__ W,
                                                   f16* __restrict__ WhT) {
  const int idx = blockIdx.x * 256 + threadIdx.x;  // 131072 total
  const int o = idx >> 9, i = idx & 511;
  WhT[idx] = (f16)W[i * OUTF + o];  // write coalesced; read L2-resident (512 KB)
}

// -------- gemm1: supT[o][m] = sum_i WhT[o][i] * Xh[m][i] --------
// A = WhT (64 o-rows), B = Xh (128 m-rows), BK=64, both staged async.
// XOR chunk swizzle: phys_chunk = logical_chunk ^ (row & 7).
__global__ __launch_bounds__(256) void gemm1(const f16* __restrict__ WhT,
                                             const f16* __restrict__ Xh,
                                             f16* __restrict__ supT) {
  __shared__ __align__(16) f16 Asm[64 * 64];
  __shared__ __align__(16) f16 Bsm[128 * 64];
  const int t = threadIdx.x;
  const int wave = t >> 6, lane = t & 63;
  const int q = lane >> 4, r = lane & 15;
  const int lrow = lane >> 3, lchunk = lane & 7;
  const int o0 = blockIdx.x * 64, m0 = blockIdx.y * 128;

  f32x4 acc[4][2];
#pragma unroll
  for (int i = 0; i < 4; ++i)
#pragma unroll
    for (int j = 0; j < 2; ++j) acc[i][j] = (f32x4){0.f, 0.f, 0.f, 0.f};

  for (int kt = 0; kt < 8; ++kt) {
    const int k0 = kt * 64;
#pragma unroll
    for (int op = 0; op < 2; ++op) {  // A: 8 KB = 2 wave-ops/wave
      const int row = (wave * 2 + op) * 8 + lrow;
      const f16* src = WhT + (size_t)(o0 + row) * INF + k0 + (lchunk ^ lrow) * 8;
      async_copy16(Asm + (wave * 2 + op) * 8 * 64, src);
    }
#pragma unroll
    for (int op = 0; op < 4; ++op) {  // B: 16 KB = 4 wave-ops/wave
      const int row = (wave * 4 + op) * 8 + lrow;
      const f16* src = Xh + (size_t)(m0 + row) * INF + k0 + (lchunk ^ lrow) * 8;
      async_copy16(Bsm + (wave * 4 + op) * 8 * 64, src);
    }
    __syncthreads();
#pragma unroll
    for (int s = 0; s < 2; ++s) {
      const int pc = ((s * 4 + q) ^ (r & 7)) * 8;
      f16x8 af[4], bf[2];
#pragma unroll
      for (int i = 0; i < 4; ++i) af[i] = *(const f16x8*)&Asm[(i * 16 + r) * 64 + pc];
#pragma unroll
      for (int j = 0; j < 2; ++j)
        bf[j] = *(const f16x8*)&Bsm[(wave * 32 + j * 16 + r) * 64 + pc];
#pragma unroll
      for (int i = 0; i < 4; ++i)
#pragma unroll
        for (int j = 0; j < 2; ++j)
          acc[i][j] = __builtin_amdgcn_mfma_f32_16x16x32_f16(af[i], bf[j],
                                                             acc[i][j], 0, 0, 0);
    }
    __syncthreads();
  }
  // C/D: row(o) = q*4+g, col(m) = r
#pragma unroll
  for (int i = 0; i < 4; ++i)
#pragma unroll
    for (int j = 0; j < 2; ++j) {
      const int m = m0 + wave * 32 + j * 16 + r;
#pragma unroll
      for (int g = 0; g < 4; ++g)
        supT[(size_t)(o0 + i * 16 + q * 4 + g) * N_NODES + m] = (f16)acc[i][j][g];
    }
}

// -------- gemm2: out[n][o] (+)= sum_m adj[n][m]^2 * supT[o][m] --------
// 64n x 256o tile, BK=64, split-K=8. LDS = 8192 + 32768 = 40960 B => 4 blocks/CU.
template <bool ATOMIC>
__global__ __launch_bounds__(256, 4) void gemm2(const float* __restrict__ adj,
                                                const f16* __restrict__ supT,
                                                float* __restrict__ outp) {
  __shared__ __align__(16) f16 Asm[64 * 64];   // [n'][k'] adj^2, XOR-swizzled
  __shared__ __align__(16) f16 Bsm[256 * 64];  // [o][k'] supT, XOR-swizzled
  const int t = threadIdx.x;
  const int wave = t >> 6, lane = t & 63;
  const int q = lane >> 4, r = lane & 15;
  const int n0 = blockIdx.x * 64;
  const size_t m_base = (size_t)blockIdx.y * MSLICE;

  f32x4 acc[4][4];
#pragma unroll
  for (int i = 0; i < 4; ++i)
#pragma unroll
    for (int j = 0; j < 4; ++j) acc[i][j] = (f32x4){0.f, 0.f, 0.f, 0.f};

  const int a_row = t >> 2;       // n' 0..63
  const int a_c0 = (t & 3) * 2;   // first of 2 logical chunks
  const float* aptr = adj + (size_t)(n0 + a_row) * N_NODES + m_base + (t & 3) * 16;
  const int b_o = wave * 64 + (lane >> 3);
  const int b_kb = lane & 7;

  for (int kt = 0; kt < MSLICE / 64; ++kt) {
    // B: async, swizzle on SOURCE chunk (dst must be base + lane*16)
#pragma unroll
    for (int j = 0; j < 8; ++j) {
      const int o = b_o + j * 8;
      const int kb = b_kb ^ (o & 7);
      const f16* src = supT + (size_t)o * N_NODES + m_base + kt * 64 + kb * 8;
      async_copy16(Bsm + (wave * 64 + j * 8) * 64, src);
    }
    // A: 16 fp32, square, cvt, 2x ds_write_b128 (XOR-swizzled chunks)
    {
      const float* ap = aptr + kt * 64;
      f32x4 v0 = *(const f32x4*)(ap + 0);
      f32x4 v1 = *(const f32x4*)(ap + 4);
      f32x4 v2 = *(const f32x4*)(ap + 8);
      f32x4 v3 = *(const f32x4*)(ap + 12);
      f16x8 h0, h1;
#pragma unroll
      for (int u = 0; u < 4; ++u) {
        h0[u] = (f16)(v0[u] * v0[u]);
        h0[4 + u] = (f16)(v1[u] * v1[u]);
        h1[u] = (f16)(v2[u] * v2[u]);
        h1[4 + u] = (f16)(v3[u] * v3[u]);
      }
      *(f16x8*)&Asm[a_row * 64 + ((a_c0 ^ (a_row & 7)) * 8)] = h0;
      *(f16x8*)&Asm[a_row * 64 + (((a_c0 + 1) ^ (a_row & 7)) * 8)] = h1;
    }
    __syncthreads();
#pragma unroll
    for (int s = 0; s < 2; ++s) {
      const int pc = ((s * 4 + q) ^ (r & 7)) * 8;
      f16x8 af[4], bf[4];
#pragma unroll
      for (int i = 0; i < 4; ++i) af[i] = *(const f16x8*)&Asm[(i * 16 + r) * 64 + pc];
#pragma unroll
      for (int j = 0; j < 4; ++j)
        bf[j] = *(const f16x8*)&Bsm[(wave * 64 + j * 16 + r) * 64 + pc];
#pragma unroll
      for (int i = 0; i < 4; ++i)
#pragma unroll
        for (int j = 0; j < 4; ++j)
          acc[i][j] = __builtin_amdgcn_mfma_f32_16x16x32_f16(af[i], bf[j],
                                                             acc[i][j], 0, 0, 0);
    }
    __syncthreads();
  }
  // epilogue
  float* base = ATOMIC ? outp : outp + (size_t)blockIdx.y * N_NODES * OUTF;
#pragma unroll
  for (int i = 0; i < 4; ++i)
#pragma unroll
    for (int g = 0; g < 4; ++g) {
      const int n = n0 + i * 16 + q * 4 + g;
      float* orow = base + (size_t)n * OUTF + wave * 64 + r;
#pragma unroll
      for (int j = 0; j < 4; ++j) {
        if (ATOMIC)
          atomicAdd(orow + j * 16, acc[i][j][g]);
        else
          orow[j * 16] = acc[i][j][g];
      }
    }
}

// -------- epilogue A: reduce 8 partials + bias + ELU --------
__global__ __launch_bounds__(256) void reduce_elu(const float* __restrict__ P,
                                                  const float* __restrict__ bias,
                                                  float* __restrict__ out) {
  const int idx = blockIdx.x * 256 + threadIdx.x;  // float4 index, 512K total
  f32x4 s = (f32x4){0.f, 0.f, 0.f, 0.f};
#pragma unroll
  for (int y = 0; y < SPLITK; ++y)
    s += ((const f32x4*)(P + (size_t)y * N_NODES * OUTF))[idx];
  const f32x4 b = ((const f32x4*)bias)[idx & 63];
  f32x4 v;
#pragma unroll
  for (int u = 0; u < 4; ++u) v[u] = elu(s[u] + b[u]);
  ((f32x4*)out)[idx] = v;
}

// -------- epilogue B (atomic fallback): in-place bias + ELU --------
__global__ __launch_bounds__(256) void bias_elu(float* __restrict__ out,
                                                const float* __restrict__ bias) {
  const int idx = blockIdx.x * 256 + threadIdx.x;
  f32x4 v = ((const f32x4*)out)[idx];
  const f32x4 b = ((const f32x4*)bias)[idx & 63];
#pragma unroll
  for (int u = 0; u < 4; ++u) v[u] = elu(v[u] + b[u]);
  ((f32x4*)out)[idx] = v;
}

extern "C" void kernel_launch(void* const* d_in, const int* in_sizes, int n_in,
                              void* d_out, int out_size, void* d_ws, size_t ws_size,
                              hipStream_t stream) {
  const float* X = (const float*)d_in[0];     // [8192, 512]
  const float* adj = (const float*)d_in[1];   // [8192, 8192]
  const float* W = (const float*)d_in[2];     // [512, 256]
  const float* bias = (const float*)d_in[3];  // [256]
  float* out = (float*)d_out;                 // [8192, 256] fp32

  char* ws = (char*)d_ws;
  f16* supT = (f16*)(ws + 0);                    // 4 MB
  f16* Xh = (f16*)(ws + (4u << 20));             // 8 MB
  f16* WhT = (f16*)(ws + (12u << 20));           // 256 KB
  float* P = (float*)(ws + (16u << 20));         // 64 MB partials
  const size_t need = (80u << 20);

  cast_x<<<N_NODES * INF / 8 / 256, 256, 0, stream>>>(X, Xh);
  transpose_w<<<INF * OUTF / 256, 256, 0, stream>>>(W, WhT);
  gemm1<<<dim3(OUTF / 64, N_NODES / 128), 256, 0, stream>>>(WhT, Xh, supT);
  if (ws_size >= need) {
    gemm2<false><<<dim3(N_NODES / 64, SPLITK), 256, 0, stream>>>(adj, supT, P);
    reduce_elu<<<N_NODES * OUTF / 4 / 256, 256, 0, stream>>>(P, bias, out);
  } else {
    hipMemsetAsync(d_out, 0, (size_t)out_size * sizeof(float), stream);
    gemm2<true><<<dim3(N_NODES / 64, SPLITK), 256, 0, stream>>>(adj, supT, out);
    bias_elu<<<N_NODES * OUTF / 4 / 256, 256, 0, stream>>>(out, bias);
  }
}

// Round 3
// 434.615 us; speedup vs baseline: 1.0369x; 1.0203x over previous
//
#include <hip/hip_runtime.h>
#include <cstdint>
#include <cstddef>

#define N_NODES 8192
#define INF 512
#define OUTF 256
#define SPLITK 8
#define MSLICE (N_NODES / SPLITK)  // 1024

typedef _Float16 f16;
typedef _Float16 f16x8 __attribute__((ext_vector_type(8)));
typedef _Float16 f16x4 __attribute__((ext_vector_type(4)));
typedef float f32x4 __attribute__((ext_vector_type(4)));

__device__ __forceinline__ void async_copy16(void* lds_dst, const void* g_src) {
  __builtin_amdgcn_global_load_lds(
      (const __attribute__((address_space(1))) void*)g_src,
      (__attribute__((address_space(3))) void*)lds_dst,
      16, 0, 0);
}

__device__ __forceinline__ float elu(float x) { return x > 0.f ? x : expm1f(x); }

// -------- prep: W [512][256] fp32 -> WhT [256][512] f16 (512 KB, tiny) -----
__global__ __launch_bounds__(256) void prep_w(const float* __restrict__ W,
                                              f16* __restrict__ WhT) {
  const int idx = blockIdx.x * 256 + threadIdx.x;  // 131072
  const int o = idx >> 9, i = idx & 511;
  WhT[idx] = (f16)W[i * OUTF + o];  // write coalesced; read via L2 (512 KB)
}

// -------- gemm1: supT[o][m] = sum_k WhT[o][k] * X[m][k]  (X cast fused) ----
// Tile 64o x 64m, BK=64, 8 iters. Grid (4,128)=512 blocks => 2/CU.
__global__ __launch_bounds__(256) void gemm1(const f16* __restrict__ WhT,
                                             const float* __restrict__ X,
                                             f16* __restrict__ supT) {
  __shared__ __align__(16) f16 Asm[64 * 64];  // WhT tile, XOR chunk-swizzled
  __shared__ __align__(16) f16 Bsm[64 * 64];  // X tile (f16), XOR-swizzled
  const int t = threadIdx.x;
  const int wave = t >> 6, lane = t & 63;
  const int q = lane >> 4, r = lane & 15;
  const int lrow = lane >> 3, lchunk = lane & 7;
  const int o0 = blockIdx.x * 64, m0 = blockIdx.y * 64;

  f32x4 acc[4];
#pragma unroll
  for (int i = 0; i < 4; ++i) acc[i] = (f32x4){0.f, 0.f, 0.f, 0.f};

  const int b_row = t >> 2;       // m' 0..63
  const int b_c0 = (t & 3) * 2;   // first of 2 logical chunks
  const float* xptr = X + (size_t)(m0 + b_row) * INF + (t & 3) * 16;

  for (int kt = 0; kt < 8; ++kt) {
    const int k0 = kt * 64;
    // A: async DMA, swizzle on source chunk (dst must be base + lane*16)
#pragma unroll
    for (int op = 0; op < 2; ++op) {
      const int row = (wave * 2 + op) * 8 + lrow;
      const f16* src = WhT + (size_t)(o0 + row) * INF + k0 + (lchunk ^ lrow) * 8;
      async_copy16(Asm + (wave * 2 + op) * 512, src);
    }
    // B: 16 fp32 per thread, cvt f16, 2x ds_write_b128 XOR-swizzled
    {
      const float* xp = xptr + k0;
      f32x4 v0 = *(const f32x4*)(xp + 0);
      f32x4 v1 = *(const f32x4*)(xp + 4);
      f32x4 v2 = *(const f32x4*)(xp + 8);
      f32x4 v3 = *(const f32x4*)(xp + 12);
      f16x8 h0, h1;
#pragma unroll
      for (int u = 0; u < 4; ++u) {
        h0[u] = (f16)v0[u];
        h0[4 + u] = (f16)v1[u];
        h1[u] = (f16)v2[u];
        h1[4 + u] = (f16)v3[u];
      }
      *(f16x8*)&Bsm[b_row * 64 + ((b_c0 ^ (b_row & 7)) * 8)] = h0;
      *(f16x8*)&Bsm[b_row * 64 + (((b_c0 + 1) ^ (b_row & 7)) * 8)] = h1;
    }
    __syncthreads();
#pragma unroll
    for (int s = 0; s < 2; ++s) {
      const int pc = ((s * 4 + q) ^ (r & 7)) * 8;
      f16x8 af[4];
#pragma unroll
      for (int i = 0; i < 4; ++i) af[i] = *(const f16x8*)&Asm[(i * 16 + r) * 64 + pc];
      const f16x8 bf = *(const f16x8*)&Bsm[(wave * 16 + r) * 64 + pc];
#pragma unroll
      for (int i = 0; i < 4; ++i)
        acc[i] = __builtin_amdgcn_mfma_f32_16x16x32_f16(af[i], bf, acc[i], 0, 0, 0);
    }
    __syncthreads();
  }
  // C/D: row(o)=q*4+g, col(m)=r
  const int m = m0 + wave * 16 + r;
#pragma unroll
  for (int i = 0; i < 4; ++i)
#pragma unroll
    for (int g = 0; g < 4; ++g)
      supT[(size_t)(o0 + i * 16 + q * 4 + g) * N_NODES + m] = (f16)acc[i][g];
}

// -------- gemm2: P16[y][n][o] = sum_{m in slice y} adj[n][m]^2 * supT[o][m] --
// 64n x 256o tile, BK=64, split-K=8. LDS = 40960 B => 4 blocks/CU.
template <bool ATOMIC>
__global__ __launch_bounds__(256, 4) void gemm2(const float* __restrict__ adj,
                                                const f16* __restrict__ supT,
                                                f16* __restrict__ P16,
                                                float* __restrict__ outp) {
  __shared__ __align__(16) f16 Asm[64 * 64];   // adj^2 tile, XOR-swizzled
  __shared__ __align__(16) f16 Bsm[256 * 64];  // supT tile, XOR-swizzled
  const int t = threadIdx.x;
  const int wave = t >> 6, lane = t & 63;
  const int q = lane >> 4, r = lane & 15;
  const int n0 = blockIdx.x * 64;
  const size_t m_base = (size_t)blockIdx.y * MSLICE;

  f32x4 acc[4][4];
#pragma unroll
  for (int i = 0; i < 4; ++i)
#pragma unroll
    for (int j = 0; j < 4; ++j) acc[i][j] = (f32x4){0.f, 0.f, 0.f, 0.f};

  const int a_row = t >> 2;
  const int a_c0 = (t & 3) * 2;
  const float* aptr = adj + (size_t)(n0 + a_row) * N_NODES + m_base + (t & 3) * 16;
  const int b_o = wave * 64 + (lane >> 3);
  const int b_kb = lane & 7;

  for (int kt = 0; kt < MSLICE / 64; ++kt) {
    // B: async DMA, swizzle on SOURCE chunk
#pragma unroll
    for (int j = 0; j < 8; ++j) {
      const int o = b_o + j * 8;
      const int kb = b_kb ^ (o & 7);
      const f16* src = supT + (size_t)o * N_NODES + m_base + kt * 64 + kb * 8;
      async_copy16(Bsm + (wave * 64 + j * 8) * 64, src);
    }
    // A: 16 fp32, square, cvt, 2x ds_write_b128 XOR-swizzled
    {
      const float* ap = aptr + kt * 64;
      f32x4 v0 = *(const f32x4*)(ap + 0);
      f32x4 v1 = *(const f32x4*)(ap + 4);
      f32x4 v2 = *(const f32x4*)(ap + 8);
      f32x4 v3 = *(const f32x4*)(ap + 12);
      f16x8 h0, h1;
#pragma unroll
      for (int u = 0; u < 4; ++u) {
        h0[u] = (f16)(v0[u] * v0[u]);
        h0[4 + u] = (f16)(v1[u] * v1[u]);
        h1[u] = (f16)(v2[u] * v2[u]);
        h1[4 + u] = (f16)(v3[u] * v3[u]);
      }
      *(f16x8*)&Asm[a_row * 64 + ((a_c0 ^ (a_row & 7)) * 8)] = h0;
      *(f16x8*)&Asm[a_row * 64 + (((a_c0 + 1) ^ (a_row & 7)) * 8)] = h1;
    }
    __syncthreads();
#pragma unroll
    for (int s = 0; s < 2; ++s) {
      const int pc = ((s * 4 + q) ^ (r & 7)) * 8;
      f16x8 af[4], bf[4];
#pragma unroll
      for (int i = 0; i < 4; ++i) af[i] = *(const f16x8*)&Asm[(i * 16 + r) * 64 + pc];
#pragma unroll
      for (int j = 0; j < 4; ++j)
        bf[j] = *(const f16x8*)&Bsm[(wave * 64 + j * 16 + r) * 64 + pc];
#pragma unroll
      for (int i = 0; i < 4; ++i)
#pragma unroll
        for (int j = 0; j < 4; ++j)
          acc[i][j] = __builtin_amdgcn_mfma_f32_16x16x32_f16(af[i], bf[j],
                                                             acc[i][j], 0, 0, 0);
    }
    __syncthreads();
  }
  if (ATOMIC) {
#pragma unroll
    for (int i = 0; i < 4; ++i)
#pragma unroll
      for (int g = 0; g < 4; ++g) {
        const int n = n0 + i * 16 + q * 4 + g;
        float* orow = outp + (size_t)n * OUTF + wave * 64 + r;
#pragma unroll
        for (int j = 0; j < 4; ++j) atomicAdd(orow + j * 16, acc[i][j][g]);
      }
  } else {
    f16* base = P16 + (size_t)blockIdx.y * N_NODES * OUTF;
#pragma unroll
    for (int i = 0; i < 4; ++i)
#pragma unroll
      for (int g = 0; g < 4; ++g) {
        const int n = n0 + i * 16 + q * 4 + g;
        f16* orow = base + (size_t)n * OUTF + wave * 64 + r;
#pragma unroll
        for (int j = 0; j < 4; ++j) orow[j * 16] = (f16)acc[i][j][g];
      }
  }
}

// -------- epilogue A: sum 8 f16 partial planes + bias + ELU --------
__global__ __launch_bounds__(256) void reduce_elu(const f16* __restrict__ P16,
                                                  const float* __restrict__ bias,
                                                  float* __restrict__ out) {
  const int idx = blockIdx.x * 256 + threadIdx.x;  // float4 index, 524288 total
  f32x4 s = (f32x4){0.f, 0.f, 0.f, 0.f};
#pragma unroll
  for (int y = 0; y < SPLITK; ++y) {
    const f16x4 h = ((const f16x4*)(P16 + (size_t)y * N_NODES * OUTF))[idx];
#pragma unroll
    for (int u = 0; u < 4; ++u) s[u] += (float)h[u];
  }
  const f32x4 b = ((const f32x4*)bias)[idx & 63];
  f32x4 v;
#pragma unroll
  for (int u = 0; u < 4; ++u) v[u] = elu(s[u] + b[u]);
  ((f32x4*)out)[idx] = v;
}

// -------- epilogue B (atomic fallback): in-place bias + ELU --------
__global__ __launch_bounds__(256) void bias_elu(float* __restrict__ out,
                                                const float* __restrict__ bias) {
  const int idx = blockIdx.x * 256 + threadIdx.x;
  f32x4 v = ((const f32x4*)out)[idx];
  const f32x4 b = ((const f32x4*)bias)[idx & 63];
#pragma unroll
  for (int u = 0; u < 4; ++u) v[u] = elu(v[u] + b[u]);
  ((f32x4*)out)[idx] = v;
}

extern "C" void kernel_launch(void* const* d_in, const int* in_sizes, int n_in,
                              void* d_out, int out_size, void* d_ws, size_t ws_size,
                              hipStream_t stream) {
  const float* X = (const float*)d_in[0];     // [8192, 512]
  const float* adj = (const float*)d_in[1];   // [8192, 8192]
  const float* W = (const float*)d_in[2];     // [512, 256]
  const float* bias = (const float*)d_in[3];  // [256]
  float* out = (float*)d_out;                 // [8192, 256] fp32

  char* ws = (char*)d_ws;
  f16* supT = (f16*)(ws + 0);           // 4 MB
  f16* WhT = (f16*)(ws + (4u << 20));   // 256 KB
  f16* P16 = (f16*)(ws + (8u << 20));   // 32 MB f16 partials
  const size_t need = (40u << 20);

  prep_w<<<INF * OUTF / 256, 256, 0, stream>>>(W, WhT);
  gemm1<<<dim3(OUTF / 64, N_NODES / 64), 256, 0, stream>>>(WhT, X, supT);
  if (ws_size >= need) {
    gemm2<false><<<dim3(N_NODES / 64, SPLITK), 256, 0, stream>>>(adj, supT, P16, nullptr);
    reduce_elu<<<N_NODES * OUTF / 4 / 256, 256, 0, stream>>>(P16, bias, out);
  } else {
    hipMemsetAsync(d_out, 0, (size_t)out_size * sizeof(float), stream);
    gemm2<true><<<dim3(N_NODES / 64, SPLITK), 256, 0, stream>>>(adj, supT, nullptr, out);
    bias_elu<<<N_NODES * OUTF / 4 / 256, 256, 0, stream>>>(out, bias);
  }
}